// Round 4
// baseline (462.427 us; speedup 1.0000x reference)
//
#include <hip/hip_runtime.h>
#include <stdint.h>

#define K_DIM 4096
#define M_TOK 8192
#define N_OUT 4096

typedef int v4i __attribute__((ext_vector_type(4)));

// ---- workspace layout (bytes) ----
// q       : int8 [8192][4096]  @ 0          (33554432)
// tw      : int8 [4096][4096]  @ 33554432   (16777216)
// rs      : float[8192]        @ 50331648   (32768)
// partial : double[256]        @ 50364416   (2048)
// wmean   : float              @ 50366464   (4)

__device__ __forceinline__ void gload_lds16(const void* g, void* l) {
    auto gp = reinterpret_cast<const __attribute__((address_space(1))) uint32_t*>(
        reinterpret_cast<uintptr_t>(g));
    auto lp = reinterpret_cast<__attribute__((address_space(3))) uint32_t*>(
        reinterpret_cast<uintptr_t>(l));
    __builtin_amdgcn_global_load_lds(gp, lp, 16, 0, 0);
}

// --- fused: blocks 0..8191 quantize one token each; blocks 8192..8447 do
// --- partial |w| sums (one double per block) ---
__global__ __launch_bounds__(256) void prep(const float* __restrict__ x,
                                            const float* __restrict__ w,
                                            int8_t* __restrict__ q,
                                            float* __restrict__ rs,
                                            double* __restrict__ partial) {
    const int b = blockIdx.x;
    const int t = threadIdx.x;
    if (b < M_TOK) {
        const float4* x4 = (const float4*)(x + (size_t)b * K_DIM);
        float4 v[4];
        float m = 0.0f;
#pragma unroll
        for (int r = 0; r < 4; ++r) {
            v[r] = x4[t + 256 * r];
            m = fmaxf(m, fmaxf(fmaxf(fabsf(v[r].x), fabsf(v[r].y)),
                               fmaxf(fabsf(v[r].z), fabsf(v[r].w))));
        }
#pragma unroll
        for (int off = 32; off; off >>= 1) m = fmaxf(m, __shfl_down(m, off, 64));
        __shared__ float wmax[4];
        __shared__ float smax;
        if ((t & 63) == 0) wmax[t >> 6] = m;
        __syncthreads();
        if (t == 0) smax = fmaxf(fmaxf(wmax[0], wmax[1]), fmaxf(wmax[2], wmax[3]));
        __syncthreads();
        const float s = 127.0f / fmaxf(smax, 1e-5f);
        char4* q4 = (char4*)(q + (size_t)b * K_DIM);
#pragma unroll
        for (int r = 0; r < 4; ++r) {
            float4 f = v[r];
            char4 c;
            c.x = (signed char)fminf(fmaxf(rintf(f.x * s), -128.0f), 127.0f);
            c.y = (signed char)fminf(fmaxf(rintf(f.y * s), -128.0f), 127.0f);
            c.z = (signed char)fminf(fmaxf(rintf(f.z * s), -128.0f), 127.0f);
            c.w = (signed char)fminf(fmaxf(rintf(f.w * s), -128.0f), 127.0f);
            q4[t + 256 * r] = c;
        }
        if (t == 0) rs[b] = 1.0f / s;
    } else {
        const int wb = b - M_TOK;  // 0..255
        const float4* w4 = (const float4*)w + (size_t)wb * 16384 + t;
        double sum = 0.0;
#pragma unroll 8
        for (int r = 0; r < 64; ++r) {
            float4 f = w4[(size_t)r * 256];
            sum += (double)(fabsf(f.x) + fabsf(f.y)) + (double)(fabsf(f.z) + fabsf(f.w));
        }
#pragma unroll
        for (int off = 32; off; off >>= 1) sum += __shfl_down(sum, off, 64);
        __shared__ double dsum[4];
        if ((t & 63) == 0) dsum[t >> 6] = sum;
        __syncthreads();
        if (t == 0) partial[wb] = dsum[0] + dsum[1] + dsum[2] + dsum[3];
    }
}

// --- ternarize: reduce 256 partials -> mean, tw = clip(round(w/mean),-1,1) ---
__global__ __launch_bounds__(256) void ternarize(const float* __restrict__ w,
                                                 int8_t* __restrict__ tw,
                                                 const double* __restrict__ partial,
                                                 float* __restrict__ wmean_out) {
    const int t = threadIdx.x;
    double d = partial[t];
#pragma unroll
    for (int off = 32; off; off >>= 1) d += __shfl_down(d, off, 64);
    __shared__ double sh[4];
    __shared__ float swsh;
    if ((t & 63) == 0) sh[t >> 6] = d;
    __syncthreads();
    if (t == 0) {
        double mean = (sh[0] + sh[1] + sh[2] + sh[3]) * (1.0 / ((double)N_OUT * (double)K_DIM));
        float wm = fmaxf((float)mean, 1e-5f);
        swsh = 1.0f / wm;
        if (blockIdx.x == 0) *wmean_out = wm;
    }
    __syncthreads();
    const float sw = swsh;
    const float4* w4 = (const float4*)w;
    char4* t4 = (char4*)tw;
    const size_t base = (size_t)blockIdx.x * 1024 + t;  // 4096 blocks x 1024 float4
#pragma unroll
    for (int r = 0; r < 4; ++r) {
        float4 f = w4[base + 256 * r];
        char4 c;
        c.x = (signed char)fminf(fmaxf(rintf(f.x * sw), -1.0f), 1.0f);
        c.y = (signed char)fminf(fmaxf(rintf(f.y * sw), -1.0f), 1.0f);
        c.z = (signed char)fminf(fmaxf(rintf(f.z * sw), -1.0f), 1.0f);
        c.w = (signed char)fminf(fmaxf(rintf(f.w * sw), -1.0f), 1.0f);
        t4[base + 256 * r] = c;
    }
}

// --- i8 GEMM: out[m,n] = (sum_k q[m,k]*tw[n,k]) * rs[m] * wmean ---
// 256x256 block tile, BK=64, 512 threads = 8 waves (4x2), wave tile 64x128.
// A-operand loaded DIRECT from global into registers (2x reuse only) with
// 1-iter register prefetch; B staged via global_load_lds into a DOUBLE-
// BUFFERED 2x16KB LDS with a SINGLE barrier per iter: prefetch into buf^1 is
// issued right after the barrier and drained one full compute phase later,
// so the vmcnt(0)-before-s_barrier drain is hidden.
// B LDS XOR swizzle (round-2 verified, 0 conflicts): content chunk c of row r
// at slot c ^ ((r>>1)&3).
__global__ __launch_bounds__(512) void gemm_i8(const int8_t* __restrict__ A,
                                               const int8_t* __restrict__ B,
                                               const float* __restrict__ rs,
                                               const float* __restrict__ wmean_p,
                                               float* __restrict__ out) {
    const int bm = blockIdx.y * 256;
    const int bn = blockIdx.x * 256;
    __shared__ int8_t Bs[2][256 * 64];
    const int t = threadIdx.x;
    const int lane = t & 63;
    const int wave = t >> 6;
    const int wm = (wave >> 1) * 64;    // 0,64,128,192
    const int wn = (wave & 1) * 128;    // 0,128
    const int fr = lane & 15;           // fragment row (m or n)
    const int kq = lane >> 4;           // 16B k-chunk within BK=64

    v4i accv[4][8] = {};

    // B staging: thread t -> row srow=t>>2 (0..127, +128 second half), swizzled src col
    const int srow = t >> 2;
    const int scol = (((t & 3) ^ ((t >> 3) & 3)) << 4);
    const int8_t* Bg0 = B + (size_t)(bn + srow) * K_DIM + scol;
    const int8_t* Bg1 = Bg0 + (size_t)128 * K_DIM;

    // A direct-from-global row pointers (one per i-tile)
    const int8_t* Arow0 = A + (size_t)(bm + wm + fr) * K_DIM + kq * 16;

    // swizzled chunk offset for B fragment reads
    const int co = ((kq ^ ((fr >> 1) & 3)) << 4);

    // prologue: stage B(k=0) into buf0, preload A fragments for k=0
    gload_lds16(Bg0, &Bs[0][t * 16]);
    gload_lds16(Bg1, &Bs[0][8192 + t * 16]);
    v4i af[4], afn[4];
#pragma unroll
    for (int i = 0; i < 4; ++i)
        af[i] = *(const v4i*)(Arow0 + (size_t)(i * 16) * K_DIM);

    int buf = 0;
    for (int k0 = 0; k0 < K_DIM; k0 += 64) {
        __syncthreads();  // buf's staging (issued last iter) drained; prior compute done
        if (k0 + 64 < K_DIM) {
            gload_lds16(Bg0 + k0 + 64, &Bs[buf ^ 1][t * 16]);
            gload_lds16(Bg1 + k0 + 64, &Bs[buf ^ 1][8192 + t * 16]);
#pragma unroll
            for (int i = 0; i < 4; ++i)
                afn[i] = *(const v4i*)(Arow0 + (size_t)(i * 16) * K_DIM + k0 + 64);
        }
        v4i bf[8];
#pragma unroll
        for (int j = 0; j < 8; ++j)
            bf[j] = *(const v4i*)(&Bs[buf][(wn + j * 16 + fr) * 64 + co]);
#pragma unroll
        for (int i = 0; i < 4; ++i)
#pragma unroll
            for (int j = 0; j < 8; ++j)
                accv[i][j] = __builtin_amdgcn_mfma_i32_16x16x64_i8(af[i], bf[j], accv[i][j], 0, 0, 0);
#pragma unroll
        for (int i = 0; i < 4; ++i) af[i] = afn[i];
        buf ^= 1;
    }

    // epilogue: C/D layout col=lane&15, row=(lane>>4)*4+reg
    const float wmean = wmean_p[0];
    const int crow0 = (lane >> 4) * 4;
    const int ccol = lane & 15;
#pragma unroll
    for (int i = 0; i < 4; ++i) {
        const int rbase = bm + wm + i * 16 + crow0;
#pragma unroll
        for (int reg = 0; reg < 4; ++reg) {
            const int r = rbase + reg;
            const float scale = rs[r] * wmean;
            float* orow = out + (size_t)r * N_OUT + bn + wn + ccol;
#pragma unroll
            for (int j = 0; j < 8; ++j)
                orow[j * 16] = (float)accv[i][j][reg] * scale;
        }
    }
}

extern "C" void kernel_launch(void* const* d_in, const int* in_sizes, int n_in,
                              void* d_out, int out_size, void* d_ws, size_t ws_size,
                              hipStream_t stream) {
    const float* x = (const float*)d_in[0];
    const float* w = (const float*)d_in[1];
    float* out = (float*)d_out;
    char* ws = (char*)d_ws;
    int8_t* q = (int8_t*)ws;
    int8_t* tw = (int8_t*)(ws + 33554432);
    float* rs = (float*)(ws + 50331648);
    double* partial = (double*)(ws + 50364416);
    float* wmean = (float*)(ws + 50366464);

    hipLaunchKernelGGL(prep, dim3(M_TOK + 256), dim3(256), 0, stream, x, w, q, rs, partial);
    hipLaunchKernelGGL(ternarize, dim3(4096), dim3(256), 0, stream, w, tw, partial, wmean);
    hipLaunchKernelGGL(gemm_i8, dim3(N_OUT / 256, M_TOK / 256), dim3(512), 0, stream, q, tw, rs, wmean, out);
}